// Round 1
// 943.745 us; speedup vs baseline: 1.3432x; 1.3432x over previous
//
#include <hip/hip_runtime.h>
#include <hip/hip_bf16.h>

// Problem constants
#define NA 1024          // atoms
#define NC 80            // feats c
#define NI 48            // irreps
#define PQ (NI*NI)       // 2304
#define M3 (PQ*NI)       // 110592
#define K3 1270
#define K3P 1280         // K3 padded to 32
#define K2 24
#define K1 3

typedef __attribute__((ext_vector_type(8))) short bf16x8;  // 8 bf16 = 4 VGPRs
typedef __attribute__((ext_vector_type(4))) float f32x4;
typedef __attribute__((ext_vector_type(4))) unsigned int u32x4;

union BFPack { bf16x8 v; __hip_bfloat162 h[4]; };
union BF4 { uint2 u; __hip_bfloat162 h[2]; };

__device__ __forceinline__ bf16x8 pack8(float a, float b, float c, float d,
                                        float e, float f, float g, float h) {
    BFPack u;
    u.h[0] = __float22bfloat162_rn(float2{a, b});
    u.h[1] = __float22bfloat162_rn(float2{c, d});
    u.h[2] = __float22bfloat162_rn(float2{e, f});
    u.h[3] = __float22bfloat162_rn(float2{g, h});
    return u.v;
}

// ---------------------------------------------------------------------------
// W3bt[c][k] = bf16(W3[k][c]), k padded 1270->1280 with zeros. 200 KB, L2-hot.
// ---------------------------------------------------------------------------
__global__ __launch_bounds__(256) void k_w3t(const float* __restrict__ W3,
                                             __hip_bfloat16* __restrict__ W3bt) {
    int c = blockIdx.x;
    for (int k = threadIdx.x; k < K3P; k += 256) {
        float v = (k < K3) ? W3[(size_t)k * NC + c] : 0.f;
        W3bt[(size_t)c * K3P + k] = __float2bfloat16(v);
    }
}

// ---------------------------------------------------------------------------
// Kernel A (MFMA): UW3tb[c][m] = bf16( sum_k U3[m][k] * W3[k][c] )
// Same structure as before; output now stored bf16 (halves write traffic and
// halves k_main's T-read traffic to 17.7 MB).
// ---------------------------------------------------------------------------
__global__ __launch_bounds__(256) void k_uw3(const float* __restrict__ U3,
                                             const __hip_bfloat16* __restrict__ W3bt,
                                             __hip_bfloat16* __restrict__ UW3tb) {
    const int t    = threadIdx.x;
    const int wave = t >> 6;
    const int lane = t & 63;
    const int row  = lane & 15;     // A: m_local / B: c_local / D: col
    const int quad = lane >> 4;

    const int m_base = blockIdx.x * 64 + wave * 16;
    const float* __restrict__ arow = U3 + (size_t)(m_base + row) * K3;

    f32x4 acc[5];
#pragma unroll
    for (int j = 0; j < 5; ++j) acc[j] = (f32x4)(0.f);

    const int kq = quad * 8;

    for (int k0 = 0; k0 < K3 - 31; k0 += 32) {   // k0 = 0..1216 (38 full iters)
        const int kb = k0 + kq;
        const float2* a2 = (const float2*)(arow + kb);   // 8B-aligned always
        float2 p0 = a2[0], p1 = a2[1], p2 = a2[2], p3 = a2[3];
        bf16x8 af = pack8(p0.x, p0.y, p1.x, p1.y, p2.x, p2.y, p3.x, p3.y);
#pragma unroll
        for (int j = 0; j < 5; ++j) {
            bf16x8 bf = *(const bf16x8*)(W3bt + (size_t)(16 * j + row) * K3P + kb);
            acc[j] = __builtin_amdgcn_mfma_f32_16x16x32_bf16(af, bf, acc[j], 0, 0, 0);
        }
    }
    {   // peel k0 = 1248: k in [1248,1280), valid k < 1270
        const int kb = 1248 + kq;
        float av[8];
#pragma unroll
        for (int j = 0; j < 8; ++j) {
            int k = kb + j;
            av[j] = (k < K3) ? arow[k] : 0.f;
        }
        bf16x8 af = pack8(av[0], av[1], av[2], av[3], av[4], av[5], av[6], av[7]);
#pragma unroll
        for (int j = 0; j < 5; ++j) {
            bf16x8 bf = *(const bf16x8*)(W3bt + (size_t)(16 * j + row) * K3P + kb);
            acc[j] = __builtin_amdgcn_mfma_f32_16x16x32_bf16(af, bf, acc[j], 0, 0, 0);
        }
    }

    // Store bf16: D[row'=quad*4+r][col=lane&15]; UW3tb layout [c][m]. 8B-aligned.
#pragma unroll
    for (int j = 0; j < 5; ++j) {
        int c = 16 * j + row;
        size_t o = (size_t)c * M3 + m_base + quad * 4;
        BF4 pk;
        pk.h[0] = __float22bfloat162_rn(float2{acc[j].x, acc[j].y});
        pk.h[1] = __float22bfloat162_rn(float2{acc[j].z, acc[j].w});
        *(uint2*)&UW3tb[o] = pk.u;
    }
}

// ---------------------------------------------------------------------------
// c2t[c][pq] = sum_k U2[pq][k] * W2[k][c]   (tiny, stays f32)
// ---------------------------------------------------------------------------
__global__ __launch_bounds__(256) void k_c2t(const float* __restrict__ U2,
                                             const float* __restrict__ W2,
                                             float* __restrict__ c2t) {
    int idx = blockIdx.x * 256 + threadIdx.x;
    if (idx >= NC * PQ) return;
    int c  = idx / PQ;
    int pq = idx - c * PQ;
    float s = 0.f;
#pragma unroll
    for (int k = 0; k < K2; ++k) s += U2[pq * K2 + k] * W2[k * NC + c];
    c2t[idx] = s;
}

// ---------------------------------------------------------------------------
// Kernel B (NEW: MFMA): per block (c, 64-atom group):
//   y[pq,n] = sum_i T[pq,i] * V[n,i]  via mfma_f32_16x16x32_bf16 (K=48 pad 64)
//   oacc[n] += (y + c2[pq]) * V[n,p] * V[n,q]   (fp32 epilogue)
// T tile (64pq x 64i bf16, XOR-swizzled LDS rows) double-clocked with register
// prefetch; V's 8 B-fragments are tile-invariant -> hoisted to VGPRs.
// Epilogue exploits: a wave's 16-pq slice never crosses a multiple of 48, so
// p is wave-uniform (broadcast read) and q is 4-aligned consecutive (f32x4).
// ---------------------------------------------------------------------------
__global__ __launch_bounds__(256) void k_main(const float* __restrict__ nf,
                                              const __hip_bfloat16* __restrict__ UW3tb,
                                              const float* __restrict__ c2t,
                                              const float* __restrict__ U1,
                                              const float* __restrict__ W1,
                                              float* __restrict__ out) {
    __shared__ __align__(16) float Vs[64 * 52];                        // fp32 V
    __shared__ __align__(16) union { unsigned short vb[64 * 64];       // bf16 V (swz)
                                     float red[64 * 17]; } VbRed;      // aliased: vb dead after frag build
    __shared__ __align__(16) unsigned short Ts[64 * 64];               // bf16 T tile (swz)
    __shared__ __align__(16) float c2s[64];
    __shared__ __align__(16) float c1s[NI];

    const int t    = threadIdx.x;
    const int wave = t >> 6;
    const int col  = t & 15;        // lane&15
    const int quad = (t >> 4) & 3;  // lane>>4

    // XCD-aware remap (round-robin bid%8 -> XCD): give each XCD 10 whole c's,
    // so the 16 n-blocks sharing one 221 KB UW3tb[c] slice hit the same L2.
    const int bid = blockIdx.x;          // 0..1279
    const int xcd = bid & 7;
    const int kb_ = bid >> 3;            // 0..159
    const int c   = xcd + 8 * (kb_ >> 4);
    const int nb  = kb_ & 15;
    const int n0  = nb * 64;

    // ---- stage V: fp32 into Vs (stride 52), bf16 into VbRed.vb (swizzled) ----
#pragma unroll
    for (int u = 0; u < 3; ++u) {
        int f   = t + 256 * u;                 // 0..767
        int row = f / 12;
        int seg = f - row * 12;
        float4 v = *(const float4*)&nf[((size_t)(n0 + row) * NC + c) * NI + seg * 4];
        *(float4*)&Vs[row * 52 + seg * 4] = v;
        BF4 pk;
        pk.h[0] = __float22bfloat162_rn(float2{v.x, v.y});
        pk.h[1] = __float22bfloat162_rn(float2{v.z, v.w});
        *(uint2*)((char*)VbRed.vb + row * 128 + ((seg * 8) ^ ((row & 7) << 4))) = pk.u;
    }
    // zero the i=48..63 pads of Vb and Ts once (swizzle maps [96,128) bijectively)
    if (t < 128) {
        int row = t >> 1;
        int off = ((6 + (t & 1)) * 16) ^ ((row & 7) << 4);
        u32x4 z = (u32x4)(0u);
        *(u32x4*)((char*)VbRed.vb + row * 128 + off) = z;
        *(u32x4*)((char*)Ts       + row * 128 + off) = z;
    }
    if (t < NI) {
        float s = 0.f;
#pragma unroll
        for (int k = 0; k < K1; ++k) s += U1[t * K1 + k] * W1[k * NC + c];
        c1s[t] = s;
    }

    // ---- prefetch T tile 0 (384 x 16B chunks, coalesced) ----
    const __hip_bfloat16* Tcb = UW3tb + (size_t)c * M3;
    u32x4 pre0, pre1;
    pre0 = *(const u32x4*)(Tcb + (size_t)t * 8);
    if (t < 128) pre1 = *(const u32x4*)(Tcb + (size_t)(t + 256) * 8);

    __syncthreads();

    // ---- build the 8 tile-invariant B-fragments: B[k=i][n] = Vb[n][i] ----
    bf16x8 bfr[2][4];
#pragma unroll
    for (int s = 0; s < 2; ++s)
#pragma unroll
        for (int g = 0; g < 4; ++g) {
            int rw = 16 * g + col;
            bfr[s][g] = *(const bf16x8*)((const char*)VbRed.vb + rw * 128 +
                                         ((s * 64 + quad * 16) ^ ((rw & 7) << 4)));
        }
    int n52[4];
#pragma unroll
    for (int g = 0; g < 4; ++g) n52[g] = (16 * g + col) * 52;

    const int arow  = 16 * wave + col;         // A-frag row (wave's pq slice)
    const int abase = arow * 128;
    const int aswz  = (arow & 7) << 4;
    const int wq16  = 16 * wave + quad * 4;    // this lane's pq_local (r=0)

    float oacc[4] = {0.f, 0.f, 0.f, 0.f};

    for (int tile = 0; tile < PQ / 64; ++tile) {
        __syncthreads();               // prev tile's A-frag reads done
        {   // write Ts from prefetch regs (swizzled rows)
            int row = t / 6, seg = t - row * 6;
            *(u32x4*)((char*)Ts + row * 128 + ((seg * 16) ^ ((row & 7) << 4))) = pre0;
            if (t < 128) {
                int f2 = t + 256;
                int row2 = f2 / 6, seg2 = f2 - row2 * 6;
                *(u32x4*)((char*)Ts + row2 * 128 + ((seg2 * 16) ^ ((row2 & 7) << 4))) = pre1;
            }
        }
        if (t < 64) c2s[t] = c2t[(size_t)c * PQ + tile * 64 + t];
        __syncthreads();

        {   // issue next tile's loads; they complete during compute
            int nt = (tile + 1 < PQ / 64) ? tile + 1 : tile;
            const __hip_bfloat16* src = Tcb + (size_t)nt * (64 * NI);
            pre0 = *(const u32x4*)(src + (size_t)t * 8);
            if (t < 128) pre1 = *(const u32x4*)(src + (size_t)(t + 256) * 8);
        }

        // ---- y = T x V^T : 2 A-frag ds_reads + 8 MFMAs ----
        f32x4 acc[4];
#pragma unroll
        for (int g = 0; g < 4; ++g) acc[g] = (f32x4)(0.f);
#pragma unroll
        for (int s = 0; s < 2; ++s) {
            bf16x8 af = *(const bf16x8*)((const char*)Ts + abase +
                                         ((s * 64 + quad * 16) ^ aswz));
#pragma unroll
            for (int g = 0; g < 4; ++g)
                acc[g] = __builtin_amdgcn_mfma_f32_16x16x32_bf16(af, bfr[s][g], acc[g], 0, 0, 0);
        }

        // ---- epilogue: oacc[n] += (y + c2) * V[n,p] * V[n,q] ----
        // pq = tile*64 + wq16 + r; p uniform over r (16-slice can't cross 48),
        // q0 = 4-aligned, so V[n,q0..q0+3] is one 16B LDS read.
        int pqb = tile * 64 + wq16;
        int p   = (pqb * 21846) >> 20;     // exact /48 for pq < 2304
        int q0  = pqb - p * 48;
        f32x4 cv = *(const f32x4*)&c2s[wq16];
#pragma unroll
        for (int g = 0; g < 4; ++g) {
            float vp = Vs[n52[g] + p];
            f32x4 vq = *(const f32x4*)&Vs[n52[g] + q0];
#pragma unroll
            for (int r = 0; r < 4; ++r)
                oacc[g] += (acc[g][r] + cv[r]) * vp * vq[r];
        }
    }

    // ---- cross-wave reduction (red aliases Vb; Vb dead since frag build) ----
    __syncthreads();
#pragma unroll
    for (int g = 0; g < 4; ++g)
        VbRed.red[(16 * g + col) * 17 + (t >> 4)] = oacc[g];
    __syncthreads();
    if (t < 64) {
        float s = 0.f;
#pragma unroll
        for (int j = 0; j < 16; ++j) s += VbRed.red[t * 17 + j];
#pragma unroll
        for (int p = 0; p < NI; ++p) s += c1s[p] * Vs[t * 52 + p];
        out[(size_t)(n0 + t) * NC + c] = s;
    }
}

// ---------------------------------------------------------------------------
extern "C" void kernel_launch(void* const* d_in, const int* in_sizes, int n_in,
                              void* d_out, int out_size, void* d_ws, size_t ws_size,
                              hipStream_t stream) {
    const float* nf = (const float*)d_in[0];
    const float* U3 = (const float*)d_in[1];
    const float* U2 = (const float*)d_in[2];
    const float* U1 = (const float*)d_in[3];
    const float* W3 = (const float*)d_in[4];
    const float* W2 = (const float*)d_in[5];
    const float* W1 = (const float*)d_in[6];
    float* out = (float*)d_out;

    __hip_bfloat16* UW3tb = (__hip_bfloat16*)d_ws;            // NC*M3*2 = 17.7 MB
    float* c2tw = (float*)((char*)d_ws + (size_t)NC * M3 * 2); // NC*PQ*4 = 0.74 MB
    // W3bt aliases the c2t buffer: used only by k_uw3, which completes before
    // k_c2t overwrites the region (same-stream ordering). 200 KB < 737 KB.
    __hip_bfloat16* W3bt = (__hip_bfloat16*)c2tw;

    k_w3t <<<NC,                    256, 0, stream>>>(W3, W3bt);
    k_uw3 <<<M3 / 64,               256, 0, stream>>>(U3, W3bt, UW3tb);
    k_c2t <<<(NC * PQ + 255) / 256, 256, 0, stream>>>(U2, W2, c2tw);
    k_main<<<NC * 16,               256, 0, stream>>>(nf, UW3tb, c2tw, U1, W1, out);
}

// Round 2
// 814.854 us; speedup vs baseline: 1.5557x; 1.1582x over previous
//
#include <hip/hip_runtime.h>
#include <hip/hip_bf16.h>

// Problem constants
#define NA 1024          // atoms
#define NC 80            // feats c
#define NI 48            // irreps
#define PQ (NI*NI)       // 2304
#define M3 (PQ*NI)       // 110592
#define K3 1270
#define K3P 1280         // K3 padded to 32
#define K2 24
#define K1 3

typedef __attribute__((ext_vector_type(8))) short bf16x8;  // 8 bf16 = 4 VGPRs
typedef __attribute__((ext_vector_type(4))) float f32x4;
typedef __attribute__((ext_vector_type(4))) unsigned int u32x4;

union BFPack { bf16x8 v; __hip_bfloat162 h[4]; };
union BF4 { uint2 u; __hip_bfloat162 h[2]; };

__device__ __forceinline__ bf16x8 pack8(float a, float b, float c, float d,
                                        float e, float f, float g, float h) {
    BFPack u;
    u.h[0] = __float22bfloat162_rn(float2{a, b});
    u.h[1] = __float22bfloat162_rn(float2{c, d});
    u.h[2] = __float22bfloat162_rn(float2{e, f});
    u.h[3] = __float22bfloat162_rn(float2{g, h});
    return u.v;
}

// ---------------------------------------------------------------------------
// W3bt[c][k] = bf16(W3[k][c]), k padded 1270->1280 with zeros. 200 KB, L2-hot.
// ---------------------------------------------------------------------------
__global__ __launch_bounds__(256) void k_w3t(const float* __restrict__ W3,
                                             __hip_bfloat16* __restrict__ W3bt) {
    int c = blockIdx.x;
    for (int k = threadIdx.x; k < K3P; k += 256) {
        float v = (k < K3) ? W3[(size_t)k * NC + c] : 0.f;
        W3bt[(size_t)c * K3P + k] = __float2bfloat16(v);
    }
}

// ---------------------------------------------------------------------------
// Kernel A v2 (LDS-staged MFMA GEMM): UW3tb[c][m] = bf16(sum_k U3[m][k]*W3[k][c])
// M=110592 (64/block), N=80, K=1270 (BK=64, 20 tiles, zero-padded tail).
// Per tile: A (64m x 64k fp32 -> bf16 cvt during staging, 8 KB) and
// B (80c x 64k bf16 slice of W3bt, 10 KB) are reg-prefetched then written to
// granule-XOR-swizzled LDS (granule ^= row&7 -> conflict-free ds_read_b128).
// Compute phase is pure LDS: per wave 2 A-frag + 10 B-frag ds_read_b128 +
// 10 MFMA. Global loads for tile t+1 issued before compute (k_main pattern).
// ---------------------------------------------------------------------------
__global__ __launch_bounds__(256) void k_uw3(const float* __restrict__ U3,
                                             const __hip_bfloat16* __restrict__ W3bt,
                                             __hip_bfloat16* __restrict__ UW3tb) {
    __shared__ __align__(16) unsigned short As[64 * 64];   // 8 KB  (swizzled)
    __shared__ __align__(16) unsigned short Bs[80 * 64];   // 10 KB (swizzled)

    const int t    = threadIdx.x;
    const int wave = t >> 6;
    const int lane = t & 63;
    const int col  = lane & 15;     // MFMA col / A-row-local / B-c-local
    const int quad = lane >> 4;

    const int m_base = blockIdx.x * 64;

    // --- staging maps ---
    // A: thread stages row ar = t>>2, k-quarter cg = t&3 (16 consecutive k)
    const int ar  = t >> 2;
    const int cg  = t & 3;
    const float* __restrict__ arow = U3 + (size_t)(m_base + ar) * K3 + cg * 16;
    // B: granules g = t, t+256, t+512(t<128); g = c*8 + gk, 640 total
    // --- compute-side A base ---
    const int rA   = 16 * wave + col;
    const int aswz = rA & 7;

    f32x4 acc[5];
#pragma unroll
    for (int j = 0; j < 5; ++j) acc[j] = (f32x4)(0.f);

    float2 preA[8];
    u32x4  preB[3];

    // ---- prefetch tile 0 (k0 = 0; all k valid) ----
#pragma unroll
    for (int j = 0; j < 8; ++j) preA[j] = *(const float2*)(arow + j * 2);
#pragma unroll
    for (int u = 0; u < 3; ++u) {
        if (u < 2 || t < 128) {
            int g = t + 256 * u;
            int c = g >> 3, gk = g & 7;
            preB[u] = *(const u32x4*)(W3bt + (size_t)c * K3P + gk * 8);
        }
    }

    for (int tile = 0; tile < 20; ++tile) {
        __syncthreads();               // prev tile's LDS reads done
        {   // write A: 2 swizzled 16-B granules (8 bf16 each)
            bf16x8 g0 = pack8(preA[0].x, preA[0].y, preA[1].x, preA[1].y,
                              preA[2].x, preA[2].y, preA[3].x, preA[3].y);
            bf16x8 g1 = pack8(preA[4].x, preA[4].y, preA[5].x, preA[5].y,
                              preA[6].x, preA[6].y, preA[7].x, preA[7].y);
            *(bf16x8*)((char*)As + ar * 128 + (((cg * 2 + 0) ^ (ar & 7)) * 16)) = g0;
            *(bf16x8*)((char*)As + ar * 128 + (((cg * 2 + 1) ^ (ar & 7)) * 16)) = g1;
        }
#pragma unroll
        for (int u = 0; u < 3; ++u) {   // write B: swizzled granules
            if (u < 2 || t < 128) {
                int g = t + 256 * u;
                int c = g >> 3, gk = g & 7;
                *(u32x4*)((char*)Bs + c * 128 + ((gk ^ (c & 7)) * 16)) = preB[u];
            }
        }
        __syncthreads();

        // ---- issue next tile's global loads; complete during compute ----
        if (tile + 1 < 20) {
            int nt = tile + 1;
            int k0 = nt * 64;
            if (nt == 19) {            // tail: k in [1216,1280), valid < 1270
#pragma unroll
                for (int j = 0; j < 8; ++j) {
                    int k = k0 + cg * 16 + j * 2;   // even; pair never straddles
                    preA[j] = (k < K3) ? *(const float2*)(arow + k0 + j * 2)
                                       : float2{0.f, 0.f};
                }
            } else {
#pragma unroll
                for (int j = 0; j < 8; ++j)
                    preA[j] = *(const float2*)(arow + k0 + j * 2);
            }
#pragma unroll
            for (int u = 0; u < 3; ++u) {
                if (u < 2 || t < 128) {
                    int g = t + 256 * u;
                    int c = g >> 3, gk = g & 7;
                    preB[u] = *(const u32x4*)(W3bt + (size_t)c * K3P + k0 + gk * 8);
                }
            }
        }

        // ---- compute: pure LDS. 2 A-frag + 10 B-frag ds_read_b128, 10 MFMA ----
#pragma unroll
        for (int s = 0; s < 2; ++s) {
            bf16x8 af = *(const bf16x8*)((const char*)As + rA * 128 +
                                         (((s * 4 + quad) ^ aswz) * 16));
#pragma unroll
            for (int j = 0; j < 5; ++j) {
                int cr = 16 * j + col;
                bf16x8 bf = *(const bf16x8*)((const char*)Bs + cr * 128 +
                                             (((s * 4 + quad) ^ (cr & 7)) * 16));
                acc[j] = __builtin_amdgcn_mfma_f32_16x16x32_bf16(af, bf, acc[j], 0, 0, 0);
            }
        }
    }

    // Store bf16: D[row'=quad*4+r][col]; UW3tb layout [c][m]. 8B-aligned.
#pragma unroll
    for (int j = 0; j < 5; ++j) {
        int c = 16 * j + col;
        size_t o = (size_t)c * M3 + m_base + 16 * wave + quad * 4;
        BF4 pk;
        pk.h[0] = __float22bfloat162_rn(float2{acc[j].x, acc[j].y});
        pk.h[1] = __float22bfloat162_rn(float2{acc[j].z, acc[j].w});
        *(uint2*)&UW3tb[o] = pk.u;
    }
}

// ---------------------------------------------------------------------------
// c2t[c][pq] = sum_k U2[pq][k] * W2[k][c]   (tiny, stays f32)
// ---------------------------------------------------------------------------
__global__ __launch_bounds__(256) void k_c2t(const float* __restrict__ U2,
                                             const float* __restrict__ W2,
                                             float* __restrict__ c2t) {
    int idx = blockIdx.x * 256 + threadIdx.x;
    if (idx >= NC * PQ) return;
    int c  = idx / PQ;
    int pq = idx - c * PQ;
    float s = 0.f;
#pragma unroll
    for (int k = 0; k < K2; ++k) s += U2[pq * K2 + k] * W2[k * NC + c];
    c2t[idx] = s;
}

// ---------------------------------------------------------------------------
// Kernel B (MFMA, unchanged from round 1): per block (c, 64-atom group):
//   y[pq,n] = sum_i T[pq,i] * V[n,i]  via mfma_f32_16x16x32_bf16 (K=48 pad 64)
//   oacc[n] += (y + c2[pq]) * V[n,p] * V[n,q]   (fp32 epilogue)
// ---------------------------------------------------------------------------
__global__ __launch_bounds__(256) void k_main(const float* __restrict__ nf,
                                              const __hip_bfloat16* __restrict__ UW3tb,
                                              const float* __restrict__ c2t,
                                              const float* __restrict__ U1,
                                              const float* __restrict__ W1,
                                              float* __restrict__ out) {
    __shared__ __align__(16) float Vs[64 * 52];                        // fp32 V
    __shared__ __align__(16) union { unsigned short vb[64 * 64];       // bf16 V (swz)
                                     float red[64 * 17]; } VbRed;      // aliased: vb dead after frag build
    __shared__ __align__(16) unsigned short Ts[64 * 64];               // bf16 T tile (swz)
    __shared__ __align__(16) float c2s[64];
    __shared__ __align__(16) float c1s[NI];

    const int t    = threadIdx.x;
    const int wave = t >> 6;
    const int col  = t & 15;        // lane&15
    const int quad = (t >> 4) & 3;  // lane>>4

    // XCD-aware remap (round-robin bid%8 -> XCD): give each XCD 10 whole c's,
    // so the 16 n-blocks sharing one 221 KB UW3tb[c] slice hit the same L2.
    const int bid = blockIdx.x;          // 0..1279
    const int xcd = bid & 7;
    const int kb_ = bid >> 3;            // 0..159
    const int c   = xcd + 8 * (kb_ >> 4);
    const int nb  = kb_ & 15;
    const int n0  = nb * 64;

    // ---- stage V: fp32 into Vs (stride 52), bf16 into VbRed.vb (swizzled) ----
#pragma unroll
    for (int u = 0; u < 3; ++u) {
        int f   = t + 256 * u;                 // 0..767
        int row = f / 12;
        int seg = f - row * 12;
        float4 v = *(const float4*)&nf[((size_t)(n0 + row) * NC + c) * NI + seg * 4];
        *(float4*)&Vs[row * 52 + seg * 4] = v;
        BF4 pk;
        pk.h[0] = __float22bfloat162_rn(float2{v.x, v.y});
        pk.h[1] = __float22bfloat162_rn(float2{v.z, v.w});
        *(uint2*)((char*)VbRed.vb + row * 128 + ((seg * 8) ^ ((row & 7) << 4))) = pk.u;
    }
    // zero the i=48..63 pads of Vb and Ts once (swizzle maps [96,128) bijectively)
    if (t < 128) {
        int row = t >> 1;
        int off = ((6 + (t & 1)) * 16) ^ ((row & 7) << 4);
        u32x4 z = (u32x4)(0u);
        *(u32x4*)((char*)VbRed.vb + row * 128 + off) = z;
        *(u32x4*)((char*)Ts       + row * 128 + off) = z;
    }
    if (t < NI) {
        float s = 0.f;
#pragma unroll
        for (int k = 0; k < K1; ++k) s += U1[t * K1 + k] * W1[k * NC + c];
        c1s[t] = s;
    }

    // ---- prefetch T tile 0 (384 x 16B chunks, coalesced) ----
    const __hip_bfloat16* Tcb = UW3tb + (size_t)c * M3;
    u32x4 pre0, pre1;
    pre0 = *(const u32x4*)(Tcb + (size_t)t * 8);
    if (t < 128) pre1 = *(const u32x4*)(Tcb + (size_t)(t + 256) * 8);

    __syncthreads();

    // ---- build the 8 tile-invariant B-fragments: B[k=i][n] = Vb[n][i] ----
    bf16x8 bfr[2][4];
#pragma unroll
    for (int s = 0; s < 2; ++s)
#pragma unroll
        for (int g = 0; g < 4; ++g) {
            int rw = 16 * g + col;
            bfr[s][g] = *(const bf16x8*)((const char*)VbRed.vb + rw * 128 +
                                         ((s * 64 + quad * 16) ^ ((rw & 7) << 4)));
        }
    int n52[4];
#pragma unroll
    for (int g = 0; g < 4; ++g) n52[g] = (16 * g + col) * 52;

    const int arow  = 16 * wave + col;         // A-frag row (wave's pq slice)
    const int abase = arow * 128;
    const int aswz  = (arow & 7) << 4;
    const int wq16  = 16 * wave + quad * 4;    // this lane's pq_local (r=0)

    float oacc[4] = {0.f, 0.f, 0.f, 0.f};

    for (int tile = 0; tile < PQ / 64; ++tile) {
        __syncthreads();               // prev tile's A-frag reads done
        {   // write Ts from prefetch regs (swizzled rows)
            int row = t / 6, seg = t - row * 6;
            *(u32x4*)((char*)Ts + row * 128 + ((seg * 16) ^ ((row & 7) << 4))) = pre0;
            if (t < 128) {
                int f2 = t + 256;
                int row2 = f2 / 6, seg2 = f2 - row2 * 6;
                *(u32x4*)((char*)Ts + row2 * 128 + ((seg2 * 16) ^ ((row2 & 7) << 4))) = pre1;
            }
        }
        if (t < 64) c2s[t] = c2t[(size_t)c * PQ + tile * 64 + t];
        __syncthreads();

        {   // issue next tile's loads; they complete during compute
            int nt = (tile + 1 < PQ / 64) ? tile + 1 : tile;
            const __hip_bfloat16* src = Tcb + (size_t)nt * (64 * NI);
            pre0 = *(const u32x4*)(src + (size_t)t * 8);
            if (t < 128) pre1 = *(const u32x4*)(src + (size_t)(t + 256) * 8);
        }

        // ---- y = T x V^T : 2 A-frag ds_reads + 8 MFMAs ----
        f32x4 acc[4];
#pragma unroll
        for (int g = 0; g < 4; ++g) acc[g] = (f32x4)(0.f);
#pragma unroll
        for (int s = 0; s < 2; ++s) {
            bf16x8 af = *(const bf16x8*)((const char*)Ts + abase +
                                         ((s * 64 + quad * 16) ^ aswz));
#pragma unroll
            for (int g = 0; g < 4; ++g)
                acc[g] = __builtin_amdgcn_mfma_f32_16x16x32_bf16(af, bfr[s][g], acc[g], 0, 0, 0);
        }

        // ---- epilogue: oacc[n] += (y + c2) * V[n,p] * V[n,q] ----
        int pqb = tile * 64 + wq16;
        int p   = (pqb * 21846) >> 20;     // exact /48 for pq < 2304
        int q0  = pqb - p * 48;
        f32x4 cv = *(const f32x4*)&c2s[wq16];
#pragma unroll
        for (int g = 0; g < 4; ++g) {
            float vp = Vs[n52[g] + p];
            f32x4 vq = *(const f32x4*)&Vs[n52[g] + q0];
#pragma unroll
            for (int r = 0; r < 4; ++r)
                oacc[g] += (acc[g][r] + cv[r]) * vp * vq[r];
        }
    }

    // ---- cross-wave reduction (red aliases Vb; Vb dead since frag build) ----
    __syncthreads();
#pragma unroll
    for (int g = 0; g < 4; ++g)
        VbRed.red[(16 * g + col) * 17 + (t >> 4)] = oacc[g];
    __syncthreads();
    if (t < 64) {
        float s = 0.f;
#pragma unroll
        for (int j = 0; j < 16; ++j) s += VbRed.red[t * 17 + j];
#pragma unroll
        for (int p = 0; p < NI; ++p) s += c1s[p] * Vs[t * 52 + p];
        out[(size_t)(n0 + t) * NC + c] = s;
    }
}

// ---------------------------------------------------------------------------
extern "C" void kernel_launch(void* const* d_in, const int* in_sizes, int n_in,
                              void* d_out, int out_size, void* d_ws, size_t ws_size,
                              hipStream_t stream) {
    const float* nf = (const float*)d_in[0];
    const float* U3 = (const float*)d_in[1];
    const float* U2 = (const float*)d_in[2];
    const float* U1 = (const float*)d_in[3];
    const float* W3 = (const float*)d_in[4];
    const float* W2 = (const float*)d_in[5];
    const float* W1 = (const float*)d_in[6];
    float* out = (float*)d_out;

    __hip_bfloat16* UW3tb = (__hip_bfloat16*)d_ws;            // NC*M3*2 = 17.7 MB
    float* c2tw = (float*)((char*)d_ws + (size_t)NC * M3 * 2); // NC*PQ*4 = 0.74 MB
    // W3bt aliases the c2t buffer: used only by k_uw3, which completes before
    // k_c2t overwrites the region (same-stream ordering). 200 KB < 737 KB.
    __hip_bfloat16* W3bt = (__hip_bfloat16*)c2tw;

    k_w3t <<<NC,                    256, 0, stream>>>(W3, W3bt);
    k_uw3 <<<M3 / 64,               256, 0, stream>>>(U3, W3bt, UW3tb);
    k_c2t <<<(NC * PQ + 255) / 256, 256, 0, stream>>>(U2, W2, c2tw);
    k_main<<<NC * 16,               256, 0, stream>>>(nf, UW3tb, c2tw, U1, W1, out);
}

// Round 3
// 810.583 us; speedup vs baseline: 1.5639x; 1.0053x over previous
//
#include <hip/hip_runtime.h>
#include <hip/hip_bf16.h>

// Problem constants
#define NA 1024          // atoms
#define NC 80            // feats c
#define NI 48            // irreps
#define PQ (NI*NI)       // 2304
#define M3 (PQ*NI)       // 110592
#define K3 1270
#define K3P 1280         // K3 padded to 32
#define K2 24
#define K1 3

typedef __attribute__((ext_vector_type(8))) short bf16x8;  // 8 bf16 = 4 VGPRs
typedef __attribute__((ext_vector_type(4))) float f32x4;
typedef __attribute__((ext_vector_type(4))) unsigned int u32x4;

union BFPack { bf16x8 v; __hip_bfloat162 h[4]; };
union BF4 { uint2 u; __hip_bfloat162 h[2]; };
union BF2 { unsigned int u; __hip_bfloat162 h; };

__device__ __forceinline__ bf16x8 pack8(float a, float b, float c, float d,
                                        float e, float f, float g, float h) {
    BFPack u;
    u.h[0] = __float22bfloat162_rn(float2{a, b});
    u.h[1] = __float22bfloat162_rn(float2{c, d});
    u.h[2] = __float22bfloat162_rn(float2{e, f});
    u.h[3] = __float22bfloat162_rn(float2{g, h});
    return u.v;
}

// ---------------------------------------------------------------------------
// W3bt[c][k] = bf16(W3[k][c]), k padded 1270->1280 with zeros. 200 KB, L2-hot.
// ---------------------------------------------------------------------------
__global__ __launch_bounds__(256) void k_w3t(const float* __restrict__ W3,
                                             __hip_bfloat16* __restrict__ W3bt) {
    int c = blockIdx.x;
    for (int k = threadIdx.x; k < K3P; k += 256) {
        float v = (k < K3) ? W3[(size_t)k * NC + c] : 0.f;
        W3bt[(size_t)c * K3P + k] = __float2bfloat16(v);
    }
}

// ---------------------------------------------------------------------------
// Kernel A v3 (LDS-staged MFMA GEMM): UW3tb[c][m] = bf16(sum_k U3[m][k]*W3[k][c])
// M=110592 (64/block), N=80, K=1280 padded (BK=128, 10 tiles).
// A staging: per sweep s, the whole WAVE covers one row's 512-B k-piece
//   (lane l -> float2 at +8l B): 9-line coalesced instructions, and the
//   ds_write_b32 lands 2 lanes/bank (conflict-free). fp32->bf16 cvt in regs.
// B staging: 16-B granules of W3bt (L2-hot), 16-line coalesced.
// LDS layout: 256-B rows of 16-B granules, granule g' = g ^ (row&7) -> A/B
//   frag ds_read_b128 hits the uniform bank floor. row&7 == col&7 for all
//   frag rows (16w ≡ 0 mod 8), so A and B share one granule offset.
// Compute per wave per tile: 4 A-frag + 20 B-frag ds_read_b128 + 20 MFMA
// (~600 cy) which covers most of the next tile's prefetch latency.
// ---------------------------------------------------------------------------
__global__ __launch_bounds__(256) void k_uw3(const float* __restrict__ U3,
                                             const __hip_bfloat16* __restrict__ W3bt,
                                             __hip_bfloat16* __restrict__ UW3tb) {
    __shared__ __align__(16) unsigned short As[64 * 128];   // 16 KB (swizzled)
    __shared__ __align__(16) unsigned short Bs[80 * 128];   // 20 KB (swizzled)

    const int t    = threadIdx.x;
    const int wave = t >> 6;
    const int lane = t & 63;
    const int col  = lane & 15;     // MFMA col / frag-row selector
    const int quad = lane >> 4;

    const int m_base = blockIdx.x * 64;

    // A staging: sweep s -> row 16*wave+s; lane covers k-pair (2*lane, 2*lane+1)
    const float* __restrict__ aw = U3 + (size_t)(m_base + 16 * wave) * K3 + 2 * lane;
    char* asw = (char*)As + (16 * wave) * 256 + (lane & 3) * 4;
    const int ag = lane >> 2;       // granule index of this lane's k-pair

    f32x4 acc[5];
#pragma unroll
    for (int j = 0; j < 5; ++j) acc[j] = (f32x4)(0.f);

    float2 preA[16];
    u32x4  preB[5];

    // ---- prefetch tile 0 (all k valid) ----
#pragma unroll
    for (int s = 0; s < 16; ++s)
        preA[s] = *(const float2*)(aw + (size_t)s * K3);
#pragma unroll
    for (int u = 0; u < 5; ++u) {
        int G = t + 256 * u, c = G >> 4, g = G & 15;
        preB[u] = *(const u32x4*)(W3bt + (size_t)c * K3P + g * 8);
    }

    for (int tile = 0; tile < 10; ++tile) {
        __syncthreads();               // prev tile's LDS reads done
        // ---- write A: 16 conflict-free b32 writes (wave-uniform row/sweep) ----
#pragma unroll
        for (int s = 0; s < 16; ++s) {
            BF2 w; w.h = __float22bfloat162_rn(preA[s]);
            *(unsigned int*)(asw + s * 256 + ((ag ^ (s & 7)) * 16)) = w.u;
        }
        // ---- write B: 5 swizzled b128 writes ----
#pragma unroll
        for (int u = 0; u < 5; ++u) {
            int G = t + 256 * u, c = G >> 4, g = G & 15;
            *(u32x4*)((char*)Bs + c * 256 + ((g ^ (c & 7)) * 16)) = preB[u];
        }
        __syncthreads();

        // ---- issue next tile's global loads; complete during compute ----
        if (tile < 9) {
            const int k0 = (tile + 1) * 128;
            const float* an = aw + k0;
            if (tile + 1 == 9) {       // tail: k in [1152,1280), valid < 1270
#pragma unroll
                for (int s = 0; s < 16; ++s)
                    preA[s] = (lane < 59) ? *(const float2*)(an + (size_t)s * K3)
                                          : float2{0.f, 0.f};
            } else {
#pragma unroll
                for (int s = 0; s < 16; ++s)
                    preA[s] = *(const float2*)(an + (size_t)s * K3);
            }
#pragma unroll
            for (int u = 0; u < 5; ++u) {
                int G = t + 256 * u, c = G >> 4, g = G & 15;
                preB[u] = *(const u32x4*)(W3bt + (size_t)c * K3P + k0 + g * 8);
            }
        }

        // ---- compute: 4 A-frag + 20 B-frag ds_read_b128, 20 MFMA ----
        const int rbase = (16 * wave + col) * 256;
#pragma unroll
        for (int ks = 0; ks < 4; ++ks) {
            const int go = ((ks * 4 + quad) ^ (col & 7)) * 16;
            bf16x8 af = *(const bf16x8*)((const char*)As + rbase + go);
#pragma unroll
            for (int j = 0; j < 5; ++j) {
                bf16x8 bf = *(const bf16x8*)((const char*)Bs + (16 * j + col) * 256 + go);
                acc[j] = __builtin_amdgcn_mfma_f32_16x16x32_bf16(af, bf, acc[j], 0, 0, 0);
            }
        }
    }

    // Store bf16: D[row'=quad*4+r][col]; UW3tb layout [c][m]. 8B-aligned.
#pragma unroll
    for (int j = 0; j < 5; ++j) {
        int c = 16 * j + col;
        size_t o = (size_t)c * M3 + m_base + 16 * wave + quad * 4;
        BF4 pk;
        pk.h[0] = __float22bfloat162_rn(float2{acc[j].x, acc[j].y});
        pk.h[1] = __float22bfloat162_rn(float2{acc[j].z, acc[j].w});
        *(uint2*)&UW3tb[o] = pk.u;
    }
}

// ---------------------------------------------------------------------------
// c2t[c][pq] = sum_k U2[pq][k] * W2[k][c]   (tiny, stays f32)
// ---------------------------------------------------------------------------
__global__ __launch_bounds__(256) void k_c2t(const float* __restrict__ U2,
                                             const float* __restrict__ W2,
                                             float* __restrict__ c2t) {
    int idx = blockIdx.x * 256 + threadIdx.x;
    if (idx >= NC * PQ) return;
    int c  = idx / PQ;
    int pq = idx - c * PQ;
    float s = 0.f;
#pragma unroll
    for (int k = 0; k < K2; ++k) s += U2[pq * K2 + k] * W2[k * NC + c];
    c2t[idx] = s;
}

// ---------------------------------------------------------------------------
// Kernel B (MFMA, unchanged — verified): per block (c, 64-atom group):
//   y[pq,n] = sum_i T[pq,i] * V[n,i]  via mfma_f32_16x16x32_bf16 (K=48 pad 64)
//   oacc[n] += (y + c2[pq]) * V[n,p] * V[n,q]   (fp32 epilogue)
// ---------------------------------------------------------------------------
__global__ __launch_bounds__(256) void k_main(const float* __restrict__ nf,
                                              const __hip_bfloat16* __restrict__ UW3tb,
                                              const float* __restrict__ c2t,
                                              const float* __restrict__ U1,
                                              const float* __restrict__ W1,
                                              float* __restrict__ out) {
    __shared__ __align__(16) float Vs[64 * 52];                        // fp32 V
    __shared__ __align__(16) union { unsigned short vb[64 * 64];       // bf16 V (swz)
                                     float red[64 * 17]; } VbRed;      // aliased: vb dead after frag build
    __shared__ __align__(16) unsigned short Ts[64 * 64];               // bf16 T tile (swz)
    __shared__ __align__(16) float c2s[64];
    __shared__ __align__(16) float c1s[NI];

    const int t    = threadIdx.x;
    const int wave = t >> 6;
    const int col  = t & 15;        // lane&15
    const int quad = (t >> 4) & 3;  // lane>>4

    // XCD-aware remap (round-robin bid%8 -> XCD): give each XCD 10 whole c's,
    // so the 16 n-blocks sharing one 221 KB UW3tb[c] slice hit the same L2.
    const int bid = blockIdx.x;          // 0..1279
    const int xcd = bid & 7;
    const int kb_ = bid >> 3;            // 0..159
    const int c   = xcd + 8 * (kb_ >> 4);
    const int nb  = kb_ & 15;
    const int n0  = nb * 64;

    // ---- stage V: fp32 into Vs (stride 52), bf16 into VbRed.vb (swizzled) ----
#pragma unroll
    for (int u = 0; u < 3; ++u) {
        int f   = t + 256 * u;                 // 0..767
        int row = f / 12;
        int seg = f - row * 12;
        float4 v = *(const float4*)&nf[((size_t)(n0 + row) * NC + c) * NI + seg * 4];
        *(float4*)&Vs[row * 52 + seg * 4] = v;
        BF4 pk;
        pk.h[0] = __float22bfloat162_rn(float2{v.x, v.y});
        pk.h[1] = __float22bfloat162_rn(float2{v.z, v.w});
        *(uint2*)((char*)VbRed.vb + row * 128 + ((seg * 8) ^ ((row & 7) << 4))) = pk.u;
    }
    // zero the i=48..63 pads of Vb and Ts once (swizzle maps [96,128) bijectively)
    if (t < 128) {
        int row = t >> 1;
        int off = ((6 + (t & 1)) * 16) ^ ((row & 7) << 4);
        u32x4 z = (u32x4)(0u);
        *(u32x4*)((char*)VbRed.vb + row * 128 + off) = z;
        *(u32x4*)((char*)Ts       + row * 128 + off) = z;
    }
    if (t < NI) {
        float s = 0.f;
#pragma unroll
        for (int k = 0; k < K1; ++k) s += U1[t * K1 + k] * W1[k * NC + c];
        c1s[t] = s;
    }

    // ---- prefetch T tile 0 (384 x 16B chunks, coalesced) ----
    const __hip_bfloat16* Tcb = UW3tb + (size_t)c * M3;
    u32x4 pre0, pre1;
    pre0 = *(const u32x4*)(Tcb + (size_t)t * 8);
    if (t < 128) pre1 = *(const u32x4*)(Tcb + (size_t)(t + 256) * 8);

    __syncthreads();

    // ---- build the 8 tile-invariant B-fragments: B[k=i][n] = Vb[n][i] ----
    bf16x8 bfr[2][4];
#pragma unroll
    for (int s = 0; s < 2; ++s)
#pragma unroll
        for (int g = 0; g < 4; ++g) {
            int rw = 16 * g + col;
            bfr[s][g] = *(const bf16x8*)((const char*)VbRed.vb + rw * 128 +
                                         ((s * 64 + quad * 16) ^ ((rw & 7) << 4)));
        }
    int n52[4];
#pragma unroll
    for (int g = 0; g < 4; ++g) n52[g] = (16 * g + col) * 52;

    const int arow  = 16 * wave + col;         // A-frag row (wave's pq slice)
    const int abase = arow * 128;
    const int aswz  = (arow & 7) << 4;
    const int wq16  = 16 * wave + quad * 4;    // this lane's pq_local (r=0)

    float oacc[4] = {0.f, 0.f, 0.f, 0.f};

    for (int tile = 0; tile < PQ / 64; ++tile) {
        __syncthreads();               // prev tile's A-frag reads done
        {   // write Ts from prefetch regs (swizzled rows)
            int row = t / 6, seg = t - row * 6;
            *(u32x4*)((char*)Ts + row * 128 + ((seg * 16) ^ ((row & 7) << 4))) = pre0;
            if (t < 128) {
                int f2 = t + 256;
                int row2 = f2 / 6, seg2 = f2 - row2 * 6;
                *(u32x4*)((char*)Ts + row2 * 128 + ((seg2 * 16) ^ ((row2 & 7) << 4))) = pre1;
            }
        }
        if (t < 64) c2s[t] = c2t[(size_t)c * PQ + tile * 64 + t];
        __syncthreads();

        {   // issue next tile's loads; they complete during compute
            int nt = (tile + 1 < PQ / 64) ? tile + 1 : tile;
            const __hip_bfloat16* src = Tcb + (size_t)nt * (64 * NI);
            pre0 = *(const u32x4*)(src + (size_t)t * 8);
            if (t < 128) pre1 = *(const u32x4*)(src + (size_t)(t + 256) * 8);
        }

        // ---- y = T x V^T : 2 A-frag ds_reads + 8 MFMAs ----
        f32x4 acc[4];
#pragma unroll
        for (int g = 0; g < 4; ++g) acc[g] = (f32x4)(0.f);
#pragma unroll
        for (int s = 0; s < 2; ++s) {
            bf16x8 af = *(const bf16x8*)((const char*)Ts + abase +
                                         ((s * 64 + quad * 16) ^ aswz));
#pragma unroll
            for (int g = 0; g < 4; ++g)
                acc[g] = __builtin_amdgcn_mfma_f32_16x16x32_bf16(af, bfr[s][g], acc[g], 0, 0, 0);
        }

        // ---- epilogue: oacc[n] += (y + c2) * V[n,p] * V[n,q] ----
        int pqb = tile * 64 + wq16;
        int p   = (pqb * 21846) >> 20;     // exact /48 for pq < 2304
        int q0  = pqb - p * 48;
        f32x4 cv = *(const f32x4*)&c2s[wq16];
#pragma unroll
        for (int g = 0; g < 4; ++g) {
            float vp = Vs[n52[g] + p];
            f32x4 vq = *(const f32x4*)&Vs[n52[g] + q0];
#pragma unroll
            for (int r = 0; r < 4; ++r)
                oacc[g] += (acc[g][r] + cv[r]) * vp * vq[r];
        }
    }

    // ---- cross-wave reduction (red aliases Vb; Vb dead since frag build) ----
    __syncthreads();
#pragma unroll
    for (int g = 0; g < 4; ++g)
        VbRed.red[(16 * g + col) * 17 + (t >> 4)] = oacc[g];
    __syncthreads();
    if (t < 64) {
        float s = 0.f;
#pragma unroll
        for (int j = 0; j < 16; ++j) s += VbRed.red[t * 17 + j];
#pragma unroll
        for (int p = 0; p < NI; ++p) s += c1s[p] * Vs[t * 52 + p];
        out[(size_t)(n0 + t) * NC + c] = s;
    }
}

// ---------------------------------------------------------------------------
extern "C" void kernel_launch(void* const* d_in, const int* in_sizes, int n_in,
                              void* d_out, int out_size, void* d_ws, size_t ws_size,
                              hipStream_t stream) {
    const float* nf = (const float*)d_in[0];
    const float* U3 = (const float*)d_in[1];
    const float* U2 = (const float*)d_in[2];
    const float* U1 = (const float*)d_in[3];
    const float* W3 = (const float*)d_in[4];
    const float* W2 = (const float*)d_in[5];
    const float* W1 = (const float*)d_in[6];
    float* out = (float*)d_out;

    __hip_bfloat16* UW3tb = (__hip_bfloat16*)d_ws;            // NC*M3*2 = 17.7 MB
    float* c2tw = (float*)((char*)d_ws + (size_t)NC * M3 * 2); // NC*PQ*4 = 0.74 MB
    // W3bt aliases the c2t buffer: used only by k_uw3, which completes before
    // k_c2t overwrites the region (same-stream ordering). 200 KB < 737 KB.
    __hip_bfloat16* W3bt = (__hip_bfloat16*)c2tw;

    k_w3t <<<NC,                    256, 0, stream>>>(W3, W3bt);
    k_uw3 <<<M3 / 64,               256, 0, stream>>>(U3, W3bt, UW3tb);
    k_c2t <<<(NC * PQ + 255) / 256, 256, 0, stream>>>(U2, W2, c2tw);
    k_main<<<NC * 16,               256, 0, stream>>>(nf, UW3tb, c2tw, U1, W1, out);
}